// Round 6
// baseline (653.269 us; speedup 1.0000x reference)
//
#include <hip/hip_runtime.h>
#include <hip/hip_bf16.h>
#include <math.h>

#define B 16384
#define K 1024
#define D 512
#define INV_T 14.285714285714286f   // 1/0.07
#define THETA 0.01f

typedef __attribute__((ext_vector_type(8))) short bf16x8;
typedef __attribute__((ext_vector_type(16))) float f32x16;
typedef unsigned long long u64;

typedef const __attribute__((address_space(1))) void* gas_ptr;
typedef __attribute__((address_space(3))) void* las_ptr;

__device__ __forceinline__ void async_copy16(const void* g, void* l) {
  __builtin_amdgcn_global_load_lds((gas_ptr)g, (las_ptr)l, 16, 0, 0);
}

// 8 floats -> hi bf16x8 + lo bf16x8 (separated). dot == zh·ch + zh·cl + zl·ch + (dropped zl·cl ~1e-4)
__device__ __forceinline__ void cvt8(const float* v, uint4& H, uint4& L) {
  unsigned h[8], l[8];
#pragma unroll
  for (int i = 0; i < 8; ++i) {
    __hip_bfloat16 hb = __float2bfloat16(v[i]);       // RNE
    float lo = v[i] - __bfloat162float(hb);           // exact
    __hip_bfloat16 lb = __float2bfloat16(lo);
    h[i] = __hip_bfloat16_raw(hb).x;
    l[i] = __hip_bfloat16_raw(lb).x;
  }
  H = make_uint4(h[0] | (h[1] << 16), h[2] | (h[3] << 16), h[4] | (h[5] << 16), h[6] | (h[7] << 16));
  L = make_uint4(l[0] | (l[1] << 16), l[2] | (l[3] << 16), l[4] | (l[5] << 16), l[6] | (l[7] << 16));
}

__device__ __forceinline__ u64 packSK(float s, int k) {
  unsigned u = __float_as_uint(s + 100000.0f);        // positive & monotone
  return ((u64)u << 32) | (unsigned)k;
}

// ---------- pack_z: z -> separated hi/lo bf16 chunks in OUT region + invn ----------
// chunk (uint4) idx = rowblk*8192 + (dcs*4 + h*2 + g)*64 + r
// content = hi/lo bf16x8 of z[rowblk*64+r][dcs*16 + g*8 .. +8]
__global__ __launch_bounds__(256) void pack_z(const float* __restrict__ z,
                                              uint4* __restrict__ zpack,
                                              float* __restrict__ invn) {
  const int bid = blockIdx.x;               // 512 blocks, 32 rows each
  const int rowblk = bid >> 1, sub = bid & 1;
  const int t = threadIdx.x;
  const int rl = t >> 3, l = t & 7;         // 8 threads per row
  const int grow = bid * 32 + rl;
  const int r = sub * 32 + rl;
  const float* zr = z + (size_t)grow * D;
  uint4* zpRB = zpack + (size_t)rowblk * 8192;
  float ss = 0.f;
#pragma unroll
  for (int it = 0; it < 8; ++it) {
    const int combo = l + it * 8;           // 0..63: dcs = combo>>1, g = combo&1
    const float4 v0 = *(const float4*)(zr + combo * 8);
    const float4 v1 = *(const float4*)(zr + combo * 8 + 4);
    float v[8] = {v0.x, v0.y, v0.z, v0.w, v1.x, v1.y, v1.z, v1.w};
#pragma unroll
    for (int i = 0; i < 8; ++i) ss = fmaf(v[i], v[i], ss);
    uint4 H, L; cvt8(v, H, L);
    const int dcs = combo >> 1, g = combo & 1;
    zpRB[(size_t)(dcs * 4 + g) * 64 + r]     = H;
    zpRB[(size_t)(dcs * 4 + 2 + g) * 64 + r] = L;
  }
  ss += __shfl_xor(ss, 1); ss += __shfl_xor(ss, 2); ss += __shfl_xor(ss, 4);
  if (l == 0) invn[grow] = 1.0f / fmaxf(sqrtf(ss), 1e-12f);
}

// ---------- pack_c: clusters -> separated hi/lo + csq ----------
// chunk idx = ((half*2+nt)*32 + dcs)*1024 + (h*2+g)*256 + c    (n = half*512 + nt*256 + c)
__global__ __launch_bounds__(64) void pack_c(const float* __restrict__ clusters,
                                             uint4* __restrict__ cpack,
                                             float* __restrict__ csq,
                                             int* __restrict__ flagCnt) {
  const int n = blockIdx.x, t = threadIdx.x;        // t = combo 0..63
  const int c = n & 255, nt = (n >> 8) & 1, half = n >> 9;
  const int dcs = t >> 1, g = t & 1;
  const float* src = clusters + (size_t)n * D + t * 8;
  const float4 a = ((const float4*)src)[0], b2 = ((const float4*)src)[1];
  float v[8] = {a.x, a.y, a.z, a.w, b2.x, b2.y, b2.z, b2.w};
  uint4 H, L; cvt8(v, H, L);
  uint4* base = cpack + ((size_t)((half * 2 + nt) * 32 + dcs)) * 1024 + c;
  base[(0 + g) * 256] = H;        // h=0 slot g
  base[(2 + g) * 256] = L;        // h=1 slot 2+g
  float sq = 0.f;
#pragma unroll
  for (int i = 0; i < 8; ++i) sq = fmaf(v[i], v[i], sq);
#pragma unroll
  for (int m = 32; m >= 1; m >>= 1) sq += __shfl_xor(sq, m);
  if (t == 0) csq[n] = sq;
  if (n == 0 && t == 0) *flagCnt = 0;
}

// ---------- main fused kernel ----------
// grid 512 = 256 rowblks x 2 col-halves; 512 thr (8 waves), 2 blocks/CU -> 4 waves/SIMD.
// Block: 64 rows x 512 cols. Wave (wr=wid>>2, wc=wid&3): 32 rows x 64 cols.
// 64 steps: nt in {0,1} x dcs in 0..31; 16 original d per step; 6 MFMA/wave/step.
__global__ __launch_bounds__(512, 4) void fused_main(
    const char* __restrict__ zpack, const char* __restrict__ cpack,
    const float* __restrict__ csqG, const float* __restrict__ invnG,
    float* __restrict__ wsPart) {
  __shared__ __align__(16) char Abuf[2][4096];    // [slot 4][r 64] chunks; slot = h*2+g
  __shared__ __align__(16) char Bbuf[2][16384];   // [slot 4][c 256] chunks
  __shared__ float invnLds[64];

  const int tid = threadIdx.x;
  const int wid = tid >> 6, lane = tid & 63;
  const int h2 = lane >> 5, c5 = lane & 31;
  const int wr = wid >> 2, wc = wid & 3;
  const int bid = blockIdx.x;
  const int rb = bid & 255, half = bid >> 8;
  const char* zpA = zpack + (size_t)rb * 131072;
  const char* cpB = cpack + (size_t)half * 1048576;

  if (tid < 64) invnLds[tid] = invnG[rb * 64 + tid] * INV_T;

  float runM[16], runS[16], bs[16];
  int bk[16];
  unsigned cflag = 0;
  f32x16 acc0, acc1;
#pragma unroll
  for (int r = 0; r < 16; ++r) {
    runM[r] = -INFINITY; runS[r] = 0.f; bs[r] = INFINITY; bk[r] = 0;
  }
#pragma unroll
  for (int i = 0; i < 16; ++i) { acc0[i] = 0.f; acc1[i] = 0.f; }

  auto STAGE = [&](int buf, int t) {
    const int dcs = t & 31;
    if (wid < 4)   // A: 256 chunks (4KB); wave wid stages slot wid
      async_copy16(zpA + (size_t)dcs * 4096 + (wid * 64 + lane) * 16,
                   Abuf[buf] + wid * 1024);
    // B: 1024 chunks (16KB), 2 per wave, linear
    const int cb0 = (wid & 3) * 128 + (wid >> 2) * 512;
    const char* bsrc = cpB + (size_t)t * 16384;
#pragma unroll
    for (int q = 0; q < 2; ++q)
      async_copy16(bsrc + (cb0 + q * 64 + lane) * 16, Bbuf[buf] + (cb0 + q * 64) * 16);
  };

  auto STEP = [&](int t, int buf) {
    if (t + 1 < 64) STAGE(buf ^ 1, t + 1);
    bf16x8 ah  = *(const bf16x8*)(Abuf[buf] + ((0 + h2) * 64 + wr * 32 + c5) * 16);
    bf16x8 al  = *(const bf16x8*)(Abuf[buf] + ((2 + h2) * 64 + wr * 32 + c5) * 16);
    bf16x8 bh0 = *(const bf16x8*)(Bbuf[buf] + ((0 + h2) * 256 + wc * 64 + c5) * 16);
    bf16x8 bl0 = *(const bf16x8*)(Bbuf[buf] + ((2 + h2) * 256 + wc * 64 + c5) * 16);
    bf16x8 bh1 = *(const bf16x8*)(Bbuf[buf] + ((0 + h2) * 256 + wc * 64 + 32 + c5) * 16);
    bf16x8 bl1 = *(const bf16x8*)(Bbuf[buf] + ((2 + h2) * 256 + wc * 64 + 32 + c5) * 16);
    acc0 = __builtin_amdgcn_mfma_f32_32x32x16_bf16(ah, bh0, acc0, 0, 0, 0);
    acc0 = __builtin_amdgcn_mfma_f32_32x32x16_bf16(ah, bl0, acc0, 0, 0, 0);
    acc0 = __builtin_amdgcn_mfma_f32_32x32x16_bf16(al, bh0, acc0, 0, 0, 0);
    acc1 = __builtin_amdgcn_mfma_f32_32x32x16_bf16(ah, bh1, acc1, 0, 0, 0);
    acc1 = __builtin_amdgcn_mfma_f32_32x32x16_bf16(ah, bl1, acc1, 0, 0, 0);
    acc1 = __builtin_amdgcn_mfma_f32_32x32x16_bf16(al, bh1, acc1, 0, 0, 0);

    if ((t & 31) == 31) {       // per-nt lane-local epilogue
      const int nt = t >> 5;
      const int kk0 = half * 512 + nt * 256 + wc * 64 + c5;
      const float cs0 = csqG[kk0], cs1 = csqG[kk0 + 32];
#pragma unroll
      for (int r = 0; r < 16; ++r) {
        const int rloc = (r & 3) + 8 * (r >> 2) + 4 * h2;
        const float invnt = invnLds[wr * 32 + rloc];
        const float l0 = acc0[r] * invnt, l1 = acc1[r] * invnt;
        const float nm = fmaxf(runM[r], fmaxf(l0, l1));
        runS[r] = runS[r] * __expf(runM[r] - nm) + __expf(l0 - nm) + __expf(l1 - nm);
        runM[r] = nm;
        const float s0 = cs0 - 2.0f * acc0[r];
        const float s1 = cs1 - 2.0f * acc1[r];
        if (fabsf(s0 - bs[r]) < THETA) cflag |= (1u << r);
        if (s0 < bs[r]) { bs[r] = s0; bk[r] = kk0; }
        if (fabsf(s1 - bs[r]) < THETA) cflag |= (1u << r);
        if (s1 < bs[r]) { bs[r] = s1; bk[r] = kk0 + 32; }
        acc0[r] = 0.f; acc1[r] = 0.f;
      }
    }
    __syncthreads();
  };

  STAGE(0, 0);
  __syncthreads();
#pragma unroll 1
  for (int tt = 0; tt < 64; tt += 2) { STEP(tt, 0); STEP(tt + 1, 1); }

  // ---- cross-lane merge (once), partials {m,s,b1,k1,flag} per (row,half) ----
  float* mrg = (float*)&Abuf[0][0];   // 4 wc * 64 rows * 5 f = 5KB (Abuf+Bbuf dead)
#pragma unroll
  for (int r = 0; r < 16; ++r) {
    float m = runM[r], s = runS[r], b1 = bs[r];
    int k1 = bk[r];
    int fl = (cflag >> r) & 1;
#pragma unroll
    for (int mk = 1; mk < 32; mk <<= 1) {
      const float om = __shfl_xor(m, mk), os = __shfl_xor(s, mk);
      const float nm = fmaxf(m, om);
      s = s * __expf(m - nm) + os * __expf(om - nm);
      m = nm;
      const float o1 = __shfl_xor(b1, mk); const int ok = __shfl_xor(k1, mk);
      const int ofl = __shfl_xor(fl, mk);
      fl = fl | ofl | (fabsf(b1 - o1) < THETA ? 1 : 0);
      if (o1 < b1 || (o1 == b1 && ok < k1)) { b1 = o1; k1 = ok; }
    }
    if (c5 == r) {
      const int row = wr * 32 + (r & 3) + 8 * (r >> 2) + 4 * h2;
      float* q = &mrg[(wc * 64 + row) * 5];
      q[0] = m; q[1] = s; q[2] = b1; q[3] = (float)k1; q[4] = (float)fl;
    }
  }
  __syncthreads();

  if (tid < 64) {
    float rm = -INFINITY, rs = 0.f, r1 = INFINITY;
    int rk = 0, rfl = 0;
#pragma unroll
    for (int w = 0; w < 4; ++w) {
      const float* q = &mrg[(w * 64 + tid) * 5];
      const float tm = q[0], ts = q[1], t1 = q[2];
      const int tk = (int)q[3], tf = (int)q[4];
      const float nm = fmaxf(rm, tm);
      rs = rs * __expf(rm - nm) + ts * __expf(tm - nm);
      rm = nm;
      rfl = rfl | tf | (fabsf(t1 - r1) < THETA ? 1 : 0);
      if (t1 < r1 || (t1 == r1 && tk < rk)) { r1 = t1; rk = tk; }
    }
    float* dst = wsPart + ((size_t)(rb * 64 + tid) * 2 + half) * 5;
    dst[0] = rm; dst[1] = rs; dst[2] = r1; dst[3] = (float)rk; dst[4] = (float)rfl;
  }
}

// ---------- merge halves + closest/flags/loss-partials + z_n stream ----------
__global__ __launch_bounds__(256) void merge_zn(
    const float* __restrict__ z, const float* __restrict__ invnG,
    const float* __restrict__ csq, const float* __restrict__ wsPart,
    float* __restrict__ out, float* __restrict__ partials,
    float* __restrict__ wsBdot, float* __restrict__ wsInvnt,
    int* __restrict__ flagCnt, int* __restrict__ flagList, u64* __restrict__ wsBest) {
  const int bid = blockIdx.x, tid = threadIdx.x;   // 256 blocks, 64 rows each
  if (tid < 64) {
    const int row = bid * 64 + tid;
    const float* p0 = wsPart + (size_t)row * 10;
    const float* p1 = p0 + 5;
    const float m0 = p0[0], s0 = p0[1], m1 = p1[0], s1 = p1[1];
    const float nm = fmaxf(m0, m1);
    const float lse = nm + logf(s0 * __expf(m0 - nm) + s1 * __expf(m1 - nm));
    const float b1a = p0[2], b1b = p1[2];
    const int k1a = (int)p0[3], k1b = (int)p1[3];
    const int fl = ((int)p0[4]) | ((int)p1[4]) | (fabsf(b1a - b1b) < THETA ? 1 : 0);
    float b1; int k1;
    if (b1b < b1a || (b1b == b1a && k1b < k1a)) { b1 = b1b; k1 = k1b; }
    else                                        { b1 = b1a; k1 = k1a; }
    const float bdot = (csq[k1] - b1) * 0.5f;
    const float invT = invnG[row] * INV_T;
    out[(size_t)B * D + row] = (float)k1;
    wsBdot[row] = bdot; wsInvnt[row] = invT;
    if (fl) { const int pos = atomicAdd(flagCnt, 1); flagList[pos] = row; wsBest[pos] = ~0ull; }
    float lossr = lse - bdot * invT;
#pragma unroll
    for (int mk = 1; mk < 64; mk <<= 1) lossr += __shfl_xor(lossr, mk);
    if (tid == 0) partials[bid] = lossr;
  }
  // z_n: 64 rows (zpack region for all rows is dead — fused complete)
  const float4* z4 = (const float4*)z + (size_t)bid * 8192;
  float4* o4 = (float4*)out + (size_t)bid * 8192;
#pragma unroll
  for (int i = 0; i < 32; ++i) {
    const int e = tid + 256 * i;
    const float inv = invnG[bid * 64 + (e >> 7)];
    float4 v = z4[e];
    v.x *= inv; v.y *= inv; v.z *= inv; v.w *= inv;
    o4[e] = v;
  }
}

// ---------- fixup: exact fp32 re-argmin; 8 blocks per flagged row ----------
__global__ __launch_bounds__(256) void fixup(
    const float* __restrict__ z, const float* __restrict__ clusters, const float* __restrict__ csq,
    const int* __restrict__ flagCnt, const int* __restrict__ flagList, u64* __restrict__ wsBest) {
  __shared__ float zrow[D];
  __shared__ float wS[4]; __shared__ int wK[4];
  const int tid = threadIdx.x;
  const int n = *flagCnt;
  const int chunk = blockIdx.x & 7;
  for (int f = blockIdx.x >> 3; f < n; f += 64) {
    const int row = flagList[f];
    __syncthreads();
    ((float2*)zrow)[tid] = ((const float2*)(z + (size_t)row * D))[tid];
    __syncthreads();
    const int k = chunk * 128 + (tid >> 1), halfsel = tid & 1;
    const float4* c4 = (const float4*)(clusters + (size_t)k * D + halfsel * 256);
    const float4* zz4 = (const float4*)(zrow + halfsel * 256);
    float dot = 0.f;
#pragma unroll 16
    for (int i = 0; i < 64; ++i) {
      const float4 cv = c4[i]; const float4 zv = zz4[i];
      dot = fmaf(cv.x, zv.x, dot); dot = fmaf(cv.y, zv.y, dot);
      dot = fmaf(cv.z, zv.z, dot); dot = fmaf(cv.w, zv.w, dot);
    }
    dot += __shfl_xor(dot, 1);
    float s = csq[k] - 2.f * dot;
    int bkv = k;
#pragma unroll
    for (int mk = 2; mk < 64; mk <<= 1) {
      const float os = __shfl_xor(s, mk); const int ok = __shfl_xor(bkv, mk);
      if (os < s || (os == s && ok < bkv)) { s = os; bkv = ok; }
    }
    if ((tid & 63) == 0) { wS[tid >> 6] = s; wK[tid >> 6] = bkv; }
    __syncthreads();
    if (tid == 0) {
      float fs = wS[0]; int fk = wK[0];
      for (int w = 1; w < 4; ++w)
        if (wS[w] < fs || (wS[w] == fs && wK[w] < fk)) { fs = wS[w]; fk = wK[w]; }
      atomicMin(&wsBest[f], packSK(fs, fk));
    }
    __syncthreads();
  }
}

// ---------- final loss reduction + flagged-row resolution ----------
__global__ __launch_bounds__(256) void loss_final(
    const float* __restrict__ partials, const float* __restrict__ csq,
    const int* __restrict__ flagCnt, const int* __restrict__ flagList,
    const u64* __restrict__ wsBest, const float* __restrict__ wsBdot,
    const float* __restrict__ wsInvnt, float* __restrict__ out) {
  const int t = threadIdx.x;
  float s = partials[t];
  const int n = *flagCnt;
  for (int f = t; f < n; f += 256) {
    const int row = flagList[f];
    const u64 v = wsBest[f];
    const int kN = (int)(unsigned)(v & 0xffffffffu);
    const float sN = __uint_as_float((unsigned)(v >> 32)) - 100000.0f;
    const int kO = (int)out[(size_t)B * D + row];
    if (kN != kO) {
      out[(size_t)B * D + row] = (float)kN;
      const float bdN = (csq[kN] - sN) * 0.5f;
      s += (wsBdot[row] - bdN) * wsInvnt[row];
    }
  }
#pragma unroll
  for (int mk = 1; mk < 64; mk <<= 1) s += __shfl_xor(s, mk);
  __shared__ float w[4];
  if ((t & 63) == 0) w[t >> 6] = s;
  __syncthreads();
  if (t == 0) out[(size_t)B * D + B] = (w[0] + w[1] + w[2] + w[3]) * (1.0f / (float)B);
}

extern "C" void kernel_launch(void* const* d_in, const int* in_sizes, int n_in,
                              void* d_out, int out_size, void* d_ws, size_t ws_size,
                              hipStream_t stream) {
  const float* z        = (const float*)d_in[0];
  const float* clusters = (const float*)d_in[1];
  float* out = (float*)d_out;

  // ws layout (~3.05 MB)
  char* wsb = (char*)d_ws;
  uint4* cpack     = (uint4*)wsb;                               // 2 MB
  u64*   wsBest    = (u64*)(wsb + (2u << 20));                  // 128 KB
  float* fb        = (float*)(wsb + (2u << 20) + (128u << 10));
  float* csq       = fb;               // 1024
  float* partials  = csq + 1024;       // 256
  float* invn      = partials + 256;   // 16384
  float* wsBdot    = invn + B;         // 16384
  float* wsInvnt   = wsBdot + B;       // 16384
  float* wsPart    = wsInvnt + B;      // 163840
  int*   flagCnt   = (int*)(wsPart + 10 * B);  // 1
  int*   flagList  = flagCnt + 1;              // 16384

  pack_c<<<K, 64, 0, stream>>>(clusters, cpack, csq, flagCnt);
  pack_z<<<B / 32, 256, 0, stream>>>(z, (uint4*)d_out, invn);
  fused_main<<<512, 512, 0, stream>>>((const char*)d_out, (const char*)cpack,
                                      csq, invn, wsPart);
  merge_zn<<<B / 64, 256, 0, stream>>>(z, invn, csq, wsPart, out, partials,
                                       wsBdot, wsInvnt, flagCnt, flagList, wsBest);
  fixup<<<512, 256, 0, stream>>>(z, clusters, csq, flagCnt, flagList, wsBest);
  loss_final<<<1, 256, 0, stream>>>(partials, csq, flagCnt, flagList, wsBest,
                                    wsBdot, wsInvnt, out);
}

// Round 8
// 298.717 us; speedup vs baseline: 2.1869x; 2.1869x over previous
//
#include <hip/hip_runtime.h>
#include <hip/hip_bf16.h>
#include <math.h>

#define B 16384
#define K 1024
#define D 512
#define INV_T 14.285714285714286f   // 1/0.07
#define THETA 0.01f

typedef __attribute__((ext_vector_type(8))) short bf16x8;
typedef __attribute__((ext_vector_type(16))) float f32x16;
typedef unsigned long long u64;

typedef const __attribute__((address_space(1))) void* gas_ptr;
typedef __attribute__((address_space(3))) void* las_ptr;

__device__ __forceinline__ void async_copy16(const void* g, void* l) {
  __builtin_amdgcn_global_load_lds((gas_ptr)g, (las_ptr)l, 16, 0, 0);
}

// 8 floats -> hi bf16x8 + lo bf16x8 (separated). dot == zh·ch + zh·cl + zl·ch (+ dropped zl·cl ~1e-4)
__device__ __forceinline__ void cvt8(const float* v, uint4& H, uint4& L) {
  unsigned h[8], l[8];
#pragma unroll
  for (int i = 0; i < 8; ++i) {
    __hip_bfloat16 hb = __float2bfloat16(v[i]);       // RNE
    float lo = v[i] - __bfloat162float(hb);           // exact
    __hip_bfloat16 lb = __float2bfloat16(lo);
    h[i] = __hip_bfloat16_raw(hb).x;
    l[i] = __hip_bfloat16_raw(lb).x;
  }
  H = make_uint4(h[0] | (h[1] << 16), h[2] | (h[3] << 16), h[4] | (h[5] << 16), h[6] | (h[7] << 16));
  L = make_uint4(l[0] | (l[1] << 16), l[2] | (l[3] << 16), l[4] | (l[5] << 16), l[6] | (l[7] << 16));
}

__device__ __forceinline__ u64 packSK(float s, int k) {
  unsigned u = __float_as_uint(s + 100000.0f);        // positive & monotone
  return ((u64)u << 32) | (unsigned)k;
}

// ---------- pack_z: z -> separated hi/lo bf16 chunks in OUT region + invn ----------
// chunk (uint4) idx = rowblk*8192 + (dcs*4 + h*2 + g)*64 + r
// content = hi/lo bf16x8 of z[rowblk*64+r][dcs*16 + g*8 .. +8]
__global__ __launch_bounds__(256) void pack_z(const float* __restrict__ z,
                                              uint4* __restrict__ zpack,
                                              float* __restrict__ invn) {
  const int bid = blockIdx.x;               // 512 blocks, 32 rows each
  const int rowblk = bid >> 1, sub = bid & 1;
  const int t = threadIdx.x;
  const int rl = t >> 3, l = t & 7;         // 8 threads per row
  const int grow = bid * 32 + rl;
  const int r = sub * 32 + rl;
  const float* zr = z + (size_t)grow * D;
  uint4* zpRB = zpack + (size_t)rowblk * 8192;
  float ss = 0.f;
#pragma unroll
  for (int it = 0; it < 8; ++it) {
    const int combo = l + it * 8;           // 0..63: dcs = combo>>1, g = combo&1
    const float4 v0 = *(const float4*)(zr + combo * 8);
    const float4 v1 = *(const float4*)(zr + combo * 8 + 4);
    float v[8] = {v0.x, v0.y, v0.z, v0.w, v1.x, v1.y, v1.z, v1.w};
#pragma unroll
    for (int i = 0; i < 8; ++i) ss = fmaf(v[i], v[i], ss);
    uint4 H, L; cvt8(v, H, L);
    const int dcs = combo >> 1, g = combo & 1;
    zpRB[(size_t)(dcs * 4 + g) * 64 + r]     = H;
    zpRB[(size_t)(dcs * 4 + 2 + g) * 64 + r] = L;
  }
  ss += __shfl_xor(ss, 1); ss += __shfl_xor(ss, 2); ss += __shfl_xor(ss, 4);
  if (l == 0) invn[grow] = 1.0f / fmaxf(sqrtf(ss), 1e-12f);
}

// ---------- pack_c: clusters -> separated hi/lo + csq ----------
// chunk idx = ((half*2+nt)*32 + dcs)*1024 + (h*2+g)*256 + c    (n = half*512 + nt*256 + c)
__global__ __launch_bounds__(64) void pack_c(const float* __restrict__ clusters,
                                             uint4* __restrict__ cpack,
                                             float* __restrict__ csq,
                                             int* __restrict__ flagCnt) {
  const int n = blockIdx.x, t = threadIdx.x;        // t = combo 0..63
  const int c = n & 255, nt = (n >> 8) & 1, half = n >> 9;
  const int dcs = t >> 1, g = t & 1;
  const float* src = clusters + (size_t)n * D + t * 8;
  const float4 a = ((const float4*)src)[0], b2 = ((const float4*)src)[1];
  float v[8] = {a.x, a.y, a.z, a.w, b2.x, b2.y, b2.z, b2.w};
  uint4 H, L; cvt8(v, H, L);
  uint4* base = cpack + ((size_t)((half * 2 + nt) * 32 + dcs)) * 1024 + c;
  base[(0 + g) * 256] = H;        // h=0 slot g
  base[(2 + g) * 256] = L;        // h=1 slot 2+g
  float sq = 0.f;
#pragma unroll
  for (int i = 0; i < 8; ++i) sq = fmaf(v[i], v[i], sq);
#pragma unroll
  for (int m = 32; m >= 1; m >>= 1) sq += __shfl_xor(sq, m);
  if (t == 0) csq[n] = sq;
  if (n == 0 && t == 0) *flagCnt = 0;
}

// ---------- main fused kernel ----------
// grid 512 = 256 rowblks x 2 col-halves; 512 thr (8 waves), 2 blocks/CU -> 4 waves/SIMD.
// Block: 64 rows x 512 cols. Wave (wr=wid>>2, wc=wid&3): 32 rows x 64 cols.
// 64 steps: nt in {0,1} x dcs in 0..31; 16 original d per step; 6 MFMA/wave/step.
__global__ __launch_bounds__(512, 4) void fused_main(
    const char* __restrict__ zpack, const char* __restrict__ cpack,
    const float* __restrict__ csqG, const float* __restrict__ invnG,
    float* __restrict__ wsPart) {
  __shared__ __align__(16) char Abuf[2][4096];    // [slot 4][r 64] chunks; slot = h*2+g
  __shared__ __align__(16) char Bbuf[2][16384];   // [slot 4][c 256] chunks
  __shared__ float invnLds[64];

  const int tid = threadIdx.x;
  const int wid = tid >> 6, lane = tid & 63;
  const int h2 = lane >> 5, c5 = lane & 31;
  const int wr = wid >> 2, wc = wid & 3;
  const int bid = blockIdx.x;
  const int rb = bid & 255, half = bid >> 8;
  const char* zpA = zpack + (size_t)rb * 131072;
  const char* cpB = cpack + (size_t)half * 1048576;

  if (tid < 64) invnLds[tid] = invnG[rb * 64 + tid] * INV_T;

  float runM[16], runS[16], bs[16], bs2[16];
  int bk[16];
  f32x16 acc0, acc1;
#pragma unroll
  for (int r = 0; r < 16; ++r) {
    runM[r] = -INFINITY; runS[r] = 0.f; bs[r] = INFINITY; bs2[r] = INFINITY; bk[r] = 0;
  }
#pragma unroll
  for (int i = 0; i < 16; ++i) { acc0[i] = 0.f; acc1[i] = 0.f; }

  auto STAGE = [&](int buf, int t) {
    const int dcs = t & 31;
    if (wid < 4)   // A: 256 chunks (4KB); wave wid stages slot wid
      async_copy16(zpA + (size_t)dcs * 4096 + (wid * 64 + lane) * 16,
                   Abuf[buf] + wid * 1024);
    // B: 1024 chunks (16KB), 2 per wave, linear
    const int cb0 = (wid & 3) * 128 + (wid >> 2) * 512;
    const char* bsrc = cpB + (size_t)t * 16384;
#pragma unroll
    for (int q = 0; q < 2; ++q)
      async_copy16(bsrc + (cb0 + q * 64 + lane) * 16, Bbuf[buf] + (cb0 + q * 64) * 16);
  };

  auto STEP = [&](int t, int buf) {
    if (t + 1 < 64) STAGE(buf ^ 1, t + 1);
    bf16x8 ah  = *(const bf16x8*)(Abuf[buf] + ((0 + h2) * 64 + wr * 32 + c5) * 16);
    bf16x8 al  = *(const bf16x8*)(Abuf[buf] + ((2 + h2) * 64 + wr * 32 + c5) * 16);
    bf16x8 bh0 = *(const bf16x8*)(Bbuf[buf] + ((0 + h2) * 256 + wc * 64 + c5) * 16);
    bf16x8 bl0 = *(const bf16x8*)(Bbuf[buf] + ((2 + h2) * 256 + wc * 64 + c5) * 16);
    bf16x8 bh1 = *(const bf16x8*)(Bbuf[buf] + ((0 + h2) * 256 + wc * 64 + 32 + c5) * 16);
    bf16x8 bl1 = *(const bf16x8*)(Bbuf[buf] + ((2 + h2) * 256 + wc * 64 + 32 + c5) * 16);
    acc0 = __builtin_amdgcn_mfma_f32_32x32x16_bf16(ah, bh0, acc0, 0, 0, 0);
    acc0 = __builtin_amdgcn_mfma_f32_32x32x16_bf16(ah, bl0, acc0, 0, 0, 0);
    acc0 = __builtin_amdgcn_mfma_f32_32x32x16_bf16(al, bh0, acc0, 0, 0, 0);
    acc1 = __builtin_amdgcn_mfma_f32_32x32x16_bf16(ah, bh1, acc1, 0, 0, 0);
    acc1 = __builtin_amdgcn_mfma_f32_32x32x16_bf16(ah, bl1, acc1, 0, 0, 0);
    acc1 = __builtin_amdgcn_mfma_f32_32x32x16_bf16(al, bh1, acc1, 0, 0, 0);

    if ((t & 31) == 31) {       // per-nt lane-local epilogue: online softmax + exact top-2
      const int nt = t >> 5;
      const int kk0 = half * 512 + nt * 256 + wc * 64 + c5;
      const float cs0 = csqG[kk0], cs1 = csqG[kk0 + 32];
#pragma unroll
      for (int r = 0; r < 16; ++r) {
        const int rloc = (r & 3) + 8 * (r >> 2) + 4 * h2;
        const float invnt = invnLds[wr * 32 + rloc];
        const float l0 = acc0[r] * invnt, l1 = acc1[r] * invnt;
        const float nm = fmaxf(runM[r], fmaxf(l0, l1));
        runS[r] = runS[r] * __expf(runM[r] - nm) + __expf(l0 - nm) + __expf(l1 - nm);
        runM[r] = nm;
        const float s0 = cs0 - 2.0f * acc0[r];
        const float s1 = cs1 - 2.0f * acc1[r];
        if (s0 < bs[r]) { bs2[r] = bs[r]; bs[r] = s0; bk[r] = kk0; }
        else            { bs2[r] = fminf(bs2[r], s0); }
        if (s1 < bs[r]) { bs2[r] = bs[r]; bs[r] = s1; bk[r] = kk0 + 32; }
        else            { bs2[r] = fminf(bs2[r], s1); }
        acc0[r] = 0.f; acc1[r] = 0.f;
      }
    }
    __syncthreads();
  };

  STAGE(0, 0);
  __syncthreads();
#pragma unroll 1
  for (int tt = 0; tt < 64; tt += 2) { STEP(tt, 0); STEP(tt + 1, 1); }

  // ---- cross-lane merge (once), partials {m,s,b1,k1,b2} per (row,half) ----
  float* mrg = (float*)&Abuf[0][0];   // 4 wc * 64 rows * 5 f = 5KB (Abuf+Bbuf dead)
#pragma unroll
  for (int r = 0; r < 16; ++r) {
    float m = runM[r], s = runS[r], b1 = bs[r], b2 = bs2[r];
    int k1 = bk[r];
#pragma unroll
    for (int mk = 1; mk < 32; mk <<= 1) {
      const float om = __shfl_xor(m, mk), os = __shfl_xor(s, mk);
      const float nm = fmaxf(m, om);
      s = s * __expf(m - nm) + os * __expf(om - nm);
      m = nm;
      const float o1 = __shfl_xor(b1, mk); const int ok = __shfl_xor(k1, mk);
      const float o2 = __shfl_xor(b2, mk);
      const bool oth = (o1 < b1) || (o1 == b1 && ok < k1);
      const float loser = oth ? b1 : o1;
      b2 = fminf(loser, fminf(b2, o2));
      if (oth) { b1 = o1; k1 = ok; }
    }
    if (c5 == r) {
      const int row = wr * 32 + (r & 3) + 8 * (r >> 2) + 4 * h2;
      float* q = &mrg[(wc * 64 + row) * 5];
      q[0] = m; q[1] = s; q[2] = b1; q[3] = (float)k1; q[4] = b2;
    }
  }
  __syncthreads();

  if (tid < 64) {
    float rm = -INFINITY, rs = 0.f, r1 = INFINITY, r2 = INFINITY;
    int rk = 0;
#pragma unroll
    for (int w = 0; w < 4; ++w) {
      const float* q = &mrg[(w * 64 + tid) * 5];
      const float tm = q[0], ts = q[1], t1 = q[2];
      const int tk = (int)q[3];
      const float t2 = q[4];
      const float nm = fmaxf(rm, tm);
      rs = rs * __expf(rm - nm) + ts * __expf(tm - nm);
      rm = nm;
      const bool oth = (t1 < r1) || (t1 == r1 && tk < rk);
      const float loser = oth ? r1 : t1;
      r2 = fminf(loser, fminf(r2, t2));
      if (oth) { r1 = t1; rk = tk; }
    }
    float* dst = wsPart + ((size_t)(rb * 64 + tid) * 2 + half) * 5;
    dst[0] = rm; dst[1] = rs; dst[2] = r1; dst[3] = (float)rk; dst[4] = r2;
  }
}

// ---------- merge halves + closest/flags/loss-partials + z_n stream ----------
__global__ __launch_bounds__(256) void merge_zn(
    const float* __restrict__ z, const float* __restrict__ invnG,
    const float* __restrict__ csq, const float* __restrict__ wsPart,
    float* __restrict__ out, float* __restrict__ partials,
    float* __restrict__ wsBdot, float* __restrict__ wsInvnt,
    int* __restrict__ flagCnt, int* __restrict__ flagList, u64* __restrict__ wsBest) {
  const int bid = blockIdx.x, tid = threadIdx.x;   // 256 blocks, 64 rows each
  if (tid < 64) {
    const int row = bid * 64 + tid;
    const float* p0 = wsPart + (size_t)row * 10;
    const float* p1 = p0 + 5;
    const float m0 = p0[0], s0 = p0[1], m1 = p1[0], s1 = p1[1];
    const float nm = fmaxf(m0, m1);
    const float lse = nm + logf(s0 * __expf(m0 - nm) + s1 * __expf(m1 - nm));
    const float b1a = p0[2], b1b = p1[2];
    const int k1a = (int)p0[3], k1b = (int)p1[3];
    const float b2a = p0[4], b2b = p1[4];
    float b1, b2; int k1;
    const bool bsel = (b1b < b1a) || (b1b == b1a && k1b < k1a);
    if (bsel) { b1 = b1b; k1 = k1b; b2 = fminf(b1a, fminf(b2a, b2b)); }
    else      { b1 = b1a; k1 = k1a; b2 = fminf(b1b, fminf(b2a, b2b)); }
    const float bdot = (csq[k1] - b1) * 0.5f;
    const float invT = invnG[row] * INV_T;
    out[(size_t)B * D + row] = (float)k1;
    wsBdot[row] = bdot; wsInvnt[row] = invT;
    if (b2 - b1 < THETA) { const int pos = atomicAdd(flagCnt, 1); flagList[pos] = row; wsBest[pos] = ~0ull; }
    float lossr = lse - bdot * invT;
#pragma unroll
    for (int mk = 1; mk < 64; mk <<= 1) lossr += __shfl_xor(lossr, mk);
    if (tid == 0) partials[bid] = lossr;
  }
  // z_n: 64 rows (zpack region for all rows is dead — fused complete)
  const float4* z4 = (const float4*)z + (size_t)bid * 8192;
  float4* o4 = (float4*)out + (size_t)bid * 8192;
#pragma unroll
  for (int i = 0; i < 32; ++i) {
    const int e = tid + 256 * i;
    const float inv = invnG[bid * 64 + (e >> 7)];
    float4 v = z4[e];
    v.x *= inv; v.y *= inv; v.z *= inv; v.w *= inv;
    o4[e] = v;
  }
}

// ---------- fixup: exact fp32 re-argmin; 8 blocks per flagged row ----------
__global__ __launch_bounds__(256) void fixup(
    const float* __restrict__ z, const float* __restrict__ clusters, const float* __restrict__ csq,
    const int* __restrict__ flagCnt, const int* __restrict__ flagList, u64* __restrict__ wsBest) {
  __shared__ float zrow[D];
  __shared__ float wS[4]; __shared__ int wK[4];
  const int tid = threadIdx.x;
  const int n = *flagCnt;
  const int chunk = blockIdx.x & 7;
  for (int f = blockIdx.x >> 3; f < n; f += 64) {
    const int row = flagList[f];
    __syncthreads();
    ((float2*)zrow)[tid] = ((const float2*)(z + (size_t)row * D))[tid];
    __syncthreads();
    const int k = chunk * 128 + (tid >> 1), halfsel = tid & 1;
    const float4* c4 = (const float4*)(clusters + (size_t)k * D + halfsel * 256);
    const float4* zz4 = (const float4*)(zrow + halfsel * 256);
    float dot = 0.f;
#pragma unroll 16
    for (int i = 0; i < 64; ++i) {
      const float4 cv = c4[i]; const float4 zv = zz4[i];
      dot = fmaf(cv.x, zv.x, dot); dot = fmaf(cv.y, zv.y, dot);
      dot = fmaf(cv.z, zv.z, dot); dot = fmaf(cv.w, zv.w, dot);
    }
    dot += __shfl_xor(dot, 1);
    float s = csq[k] - 2.f * dot;
    int bkv = k;
#pragma unroll
    for (int mk = 2; mk < 64; mk <<= 1) {
      const float os = __shfl_xor(s, mk); const int ok = __shfl_xor(bkv, mk);
      if (os < s || (os == s && ok < bkv)) { s = os; bkv = ok; }
    }
    if ((tid & 63) == 0) { wS[tid >> 6] = s; wK[tid >> 6] = bkv; }
    __syncthreads();
    if (tid == 0) {
      float fs = wS[0]; int fk = wK[0];
      for (int w = 1; w < 4; ++w)
        if (wS[w] < fs || (wS[w] == fs && wK[w] < fk)) { fs = wS[w]; fk = wK[w]; }
      atomicMin(&wsBest[f], packSK(fs, fk));
    }
    __syncthreads();
  }
}

// ---------- final loss reduction + flagged-row resolution ----------
__global__ __launch_bounds__(256) void loss_final(
    const float* __restrict__ partials, const float* __restrict__ csq,
    const int* __restrict__ flagCnt, const int* __restrict__ flagList,
    const u64* __restrict__ wsBest, const float* __restrict__ wsBdot,
    const float* __restrict__ wsInvnt, float* __restrict__ out) {
  const int t = threadIdx.x;
  float s = partials[t];
  const int n = *flagCnt;
  for (int f = t; f < n; f += 256) {
    const int row = flagList[f];
    const u64 v = wsBest[f];
    const int kN = (int)(unsigned)(v & 0xffffffffu);
    const float sN = __uint_as_float((unsigned)(v >> 32)) - 100000.0f;
    const int kO = (int)out[(size_t)B * D + row];
    if (kN != kO) {
      out[(size_t)B * D + row] = (float)kN;
      const float bdN = (csq[kN] - sN) * 0.5f;
      s += (wsBdot[row] - bdN) * wsInvnt[row];
    }
  }
#pragma unroll
  for (int mk = 1; mk < 64; mk <<= 1) s += __shfl_xor(s, mk);
  __shared__ float w[4];
  if ((t & 63) == 0) w[t >> 6] = s;
  __syncthreads();
  if (t == 0) out[(size_t)B * D + B] = (w[0] + w[1] + w[2] + w[3]) * (1.0f / (float)B);
}

extern "C" void kernel_launch(void* const* d_in, const int* in_sizes, int n_in,
                              void* d_out, int out_size, void* d_ws, size_t ws_size,
                              hipStream_t stream) {
  const float* z        = (const float*)d_in[0];
  const float* clusters = (const float*)d_in[1];
  float* out = (float*)d_out;

  // ws layout (~3.05 MB)
  char* wsb = (char*)d_ws;
  uint4* cpack     = (uint4*)wsb;                               // 2 MB
  u64*   wsBest    = (u64*)(wsb + (2u << 20));                  // 128 KB
  float* fb        = (float*)(wsb + (2u << 20) + (128u << 10));
  float* csq       = fb;               // 1024
  float* partials  = csq + 1024;       // 256
  float* invn      = partials + 256;   // 16384
  float* wsBdot    = invn + B;         // 16384
  float* wsInvnt   = wsBdot + B;       // 16384
  float* wsPart    = wsInvnt + B;      // 163840
  int*   flagCnt   = (int*)(wsPart + 10 * B);  // 1
  int*   flagList  = flagCnt + 1;              // 16384

  pack_c<<<K, 64, 0, stream>>>(clusters, cpack, csq, flagCnt);
  pack_z<<<B / 32, 256, 0, stream>>>(z, (uint4*)d_out, invn);
  fused_main<<<512, 512, 0, stream>>>((const char*)d_out, (const char*)cpack,
                                      csq, invn, wsPart);
  merge_zn<<<B / 64, 256, 0, stream>>>(z, invn, csq, wsPart, out, partials,
                                       wsBdot, wsInvnt, flagCnt, flagList, wsBest);
  fixup<<<512, 256, 0, stream>>>(z, clusters, csq, flagCnt, flagList, wsBest);
  loss_final<<<1, 256, 0, stream>>>(partials, csq, flagCnt, flagList, wsBest,
                                    wsBdot, wsInvnt, out);
}